// Round 5
// baseline (19060.205 us; speedup 1.0000x reference)
//
#include <hip/hip_runtime.h>

#define T_STEPS 1000
#define BATCH   256
#define NIN     128
#define NHID    512
#define NOUT    128
#define GROUPS  8                  // independent 32-row batch groups
#define GBLK    4                  // blocks per group (each owns 128 hidden cols)
#define GROWS   32                 // batch rows per group
#define SLOTH   (GROWS * NHID)     // 16384 halves = 32 KiB per ring slot
#define NBLK    (GROUPS * GBLK)    // 32 worker blocks

typedef _Float16 half8    __attribute__((ext_vector_type(8)));
typedef float    floatx4  __attribute__((ext_vector_type(4)));
typedef float    floatx16 __attribute__((ext_vector_type(16)));
typedef unsigned long long u64;
typedef u64      u64x2    __attribute__((ext_vector_type(2)));

__device__ __forceinline__ half8 f8_to_h8(const float* __restrict__ p) {
  floatx4 lo = *(const floatx4*)p;
  floatx4 hi = *(const floatx4*)(p + 4);
  half8 r;
#pragma unroll
  for (int i = 0; i < 4; ++i) { r[i] = (_Float16)lo[i]; r[i + 4] = (_Float16)hi[i]; }
  return r;
}

// coherent (agent-scope, LLC-fresh) 16B load of 8 fp16 — bypasses stale L1/L2
__device__ __forceinline__ half8 load_s16(const u64* p) {
  u64x2 t;
  t[0] = __hip_atomic_load(p,     __ATOMIC_RELAXED, __HIP_MEMORY_SCOPE_AGENT);
  t[1] = __hip_atomic_load(p + 1, __ATOMIC_RELAXED, __HIP_MEMORY_SCOPE_AGENT);
  return __builtin_bit_cast(half8, t);
}

// -------- init: zero flags (4 KiB) + all ring slots (768 KiB) ---------------
// 193 blocks * 256 threads * 16B = 790528 B = exactly 4096 + 24*32768.
__global__ void init_ws_kernel(int4* ws) {
  size_t idx = (size_t)blockIdx.x * blockDim.x + threadIdx.x;
  ws[idx] = make_int4(0, 0, 0, 0);
}

// ---------------- persistent fused kernel: 8 independent groups of 4 --------
// Recurrence (per wave, one 32x32 tile): mfma_f32_32x32x16_f16
//   A-frag: row=lane&31, k=(lane>>5)*8+j. C/D: col=lane&31, row=(reg&3)+8*(reg>>2)+4*(lane>>5).
// Readout (per wave, one 16x16 tile): mfma_f32_16x16x32_f16
//   A/B frag: row=lane&15, k=(lane>>4)*8+j. C/D: col=lane&15, row=(lane>>4)*4+reg.
__global__ __launch_bounds__(256, 1) void bnn_persistent_kernel(
    const float* __restrict__ X,     // [T,B,NIN]
    const float* __restrict__ Win,   // [NHID,NIN]
    const float* __restrict__ bin,   // [NHID]
    const float* __restrict__ Wrec,  // [NHID,NHID]
    const float* __restrict__ Wout,  // [NOUT,NHID]
    const float* __restrict__ bout,  // [NOUT]
    float* __restrict__ out,         // [T,B,NOUT]
    _Float16* __restrict__ slots,    // GROUPS * 3 * SLOTH fp16 ring
    unsigned int* __restrict__ flags)// GROUPS*GBLK flags, 64B apart
{
  const int tid = threadIdx.x;
  const int l   = tid & 63;
  const int w   = tid >> 6;
  const int ln  = l & 31;
  const int lk  = (l >> 5) * 8;
  const int g   = blockIdx.x >> 2;          // group 0..7 (batch rows g*32..+31)
  const int j   = blockIdx.x & 3;           // hidden-col block within group
  const int n0  = j * 128 + w * 32;         // hidden cols of this wave's tile
  const int rb  = g * GROWS;                // global batch row base

  // ---- resident weight fragments (plain cached loads, f32 -> fp16 once) ----
  half8 wr[32];
#pragma unroll
  for (int kk = 0; kk < 32; ++kk)
    wr[kk] = f8_to_h8(Wrec + (size_t)(n0 + ln) * NHID + kk * 16 + lk);
  half8 wi[8];
#pragma unroll
  for (int kk = 0; kk < 8; ++kk)
    wi[kk] = f8_to_h8(Win + (size_t)(n0 + ln) * NIN + kk * 16 + lk);
  const float binv = bin[n0 + ln];

  // ---- readout tile: 16 waves/group cover [32 rows x 128 cols] in 16x16 ----
  const int wid = j * 4 + w;                // 0..15 within group
  const int mo  = (wid >> 3) * 16;          // local batch row tile (0 or 16)
  const int no  = (wid & 7) * 16;           // out col tile
  const int l16 = l & 15;
  const int q   = l >> 4;                   // quad 0..3
  const float bo = bout[no + l16];

  // ---- GLIFR state in registers (C-layout positions) ----
  float v[16], a0[16], a1[16], sp[16];
#pragma unroll
  for (int r = 0; r < 16; ++r) { v[r] = 0.f; a0[r] = 0.f; a1[r] = 0.f; sp[r] = 0.f; }

  const int   mbase = 4 * (l >> 5);         // local row base within 32
  const float C_VI  = (float)(0.05 * 0.2 * (0.1 + 1.0 / 512.0));  // DT*K_M*R_HID

  _Float16* const gslots = slots + (size_t)g * 3 * SLOTH;
  unsigned int* const myflag = flags + (g * GBLK + j) * 16;
  const unsigned int* const pollf = flags + (g * GBLK + (l & 3)) * 16;

  for (int t = 0; t <= T_STEPS; ++t) {
    // ---- input projection for step t (cached plain loads; pre-wait) ----
    floatx16 acc;
    if (t < T_STEPS) {
      const float* xt = X + (size_t)t * (BATCH * NIN) + (size_t)(rb + ln) * NIN + lk;
      half8 ax[8];
#pragma unroll
      for (int kk = 0; kk < 8; ++kk) ax[kk] = f8_to_h8(xt + kk * 16);
#pragma unroll
      for (int i = 0; i < 16; ++i) acc[i] = binv;
#pragma unroll
      for (int kk = 0; kk < 8; ++kk)
        acc = __builtin_amdgcn_mfma_f32_32x32x16_f16(ax[kk], wi[kk], acc, 0, 0, 0);
    }

    // ---- group barrier: all 4 blocks posted flag >= t (no RMW, 4 lines) ----
    if (w == 0) {
      while (!__all((int)(__hip_atomic_load(pollf, __ATOMIC_RELAXED,
                                            __HIP_MEMORY_SCOPE_AGENT) >= (unsigned)t))) {}
    }
    __syncthreads();

    const _Float16* Sprev = gslots + (size_t)(t % 3) * SLOTH;   // s_{t-1}

    if (t < T_STEPS) {
      // ---- recurrence from s_{t-1}: coherent u64 loads -> MFMA chain ----
      const u64* sp64 = (const u64*)(Sprev + (size_t)ln * NHID) + (lk >> 2);
#pragma unroll
      for (int kk = 0; kk < 32; ++kk) {
        half8 as = load_s16(sp64 + kk * 4);
        acc = __builtin_amdgcn_mfma_f32_32x32x16_f16(as, wr[kk], acc, 0, 0, 0);
      }

      // ---- GLIFR update; coherent packed stores of s_t ----
      unsigned int* Scur32 = (unsigned int*)(gslots + (size_t)((t + 1) % 3) * SLOTH);
#pragma unroll
      for (int r = 0; r < 16; ++r) {
        const float y  = 0.5f * acc[r];                  // avg of the 2 inputs
        a0[r] = a0[r] * 0.85f - 0.05f * sp[r];           // 1-DT*3,   DT*1*(-1)
        a1[r] = a1[r] * -0.5f - 0.05f * sp[r];           // 1-DT*30,  DT*(-1)*1
        const float it = y + a0[r] + a1[r] + 700.0f;     // + I0
        v[r] = v[r] * 0.99f * (1.0f - 0.05f * sp[r]) + C_VI * it;
        const float s = 20.0f / (1.0f + __expf(-0.02f * v[r]));  // 20*sigmoid(v/50)
        sp[r] = s;
        const float sn = __shfl_xor(s, 1);               // partner col's s
        if (!(l & 1)) {                                  // even lane packs (ln, ln+1)
          const unsigned short h0 = __builtin_bit_cast(unsigned short, (_Float16)s);
          const unsigned short h1 = __builtin_bit_cast(unsigned short, (_Float16)sn);
          const unsigned int   pk = (unsigned int)h0 | ((unsigned int)h1 << 16);
          const int m = mbase + (r & 3) + 8 * (r >> 2);
          __hip_atomic_store(Scur32 + (((size_t)m * NHID + n0 + ln) >> 1), pk,
                             __ATOMIC_RELAXED, __HIP_MEMORY_SCOPE_AGENT);
        }
      }
    }

    // ---- arrive: barrier drained vmcnt -> stores at LLC; post flag t+1 ----
    __syncthreads();
    if (tid == 0 && t < T_STEPS)
      __hip_atomic_store(myflag, (unsigned int)(t + 1),
                         __ATOMIC_RELAXED, __HIP_MEMORY_SCOPE_AGENT);

    // ---- readout of out_{t-1} (off critical path; Wout streamed from L2) ----
    if (t >= 1) {
      floatx4 oacc;
#pragma unroll
      for (int r = 0; r < 4; ++r) oacc[r] = bo;
      const u64* rp64 = (const u64*)(Sprev + (size_t)(mo + l16) * NHID) + q * 2;
#pragma unroll
      for (int kk = 0; kk < 16; ++kk) {
        half8 a  = load_s16(rp64 + kk * 8);
        half8 wk = f8_to_h8(Wout + (size_t)(no + l16) * NHID + kk * 32 + q * 8);
        oacc = __builtin_amdgcn_mfma_f32_16x16x32_f16(a, wk, oacc, 0, 0, 0);
      }
      float* op = out + ((size_t)(t - 1) * BATCH + rb + mo) * NOUT + no;
#pragma unroll
      for (int r = 0; r < 4; ++r)
        op[(size_t)(q * 4 + r) * NOUT + l16] = oacc[r];
    }
  }
}

extern "C" void kernel_launch(void* const* d_in, const int* in_sizes, int n_in,
                              void* d_out, int out_size, void* d_ws, size_t ws_size,
                              hipStream_t stream) {
  const float* X    = (const float*)d_in[0];
  const float* Win  = (const float*)d_in[1];
  const float* bin  = (const float*)d_in[2];
  const float* Wrec = (const float*)d_in[3];
  const float* Wout = (const float*)d_in[4];
  const float* bout = (const float*)d_in[5];
  float* out = (float*)d_out;

  unsigned int* flags = (unsigned int*)d_ws;                  // 4 KiB reserved
  _Float16* slots = (_Float16*)((char*)d_ws + 4096);          // 24 slots = 768 KiB

  hipLaunchKernelGGL(init_ws_kernel, dim3(193), dim3(256), 0, stream, (int4*)d_ws);
  hipLaunchKernelGGL(bnn_persistent_kernel, dim3(NBLK), dim3(256), 0, stream,
                     X, Win, bin, Wrec, Wout, bout, out, slots, flags);
}